// Round 1
// baseline (728.282 us; speedup 1.0000x reference)
//
#include <hip/hip_runtime.h>

// Problem constants (fixed in reference setup_inputs)
#define FEAT_C 128
#define NB     4
#define NYv    512
#define NXv    512
// NX/64 = 8 x-segments per row

// ---------------------------------------------------------------------------
// Kernel 1: scatter voxel ids into idx_map with last-write-wins (max id wins,
// matching numpy fancy-assignment duplicate semantics).
// idx_map pre-initialized to -1 (0xFF memset).
// ---------------------------------------------------------------------------
__global__ void scatter_ids(const int4* __restrict__ coors,
                            int* __restrict__ idx_map, int n) {
    int i = blockIdx.x * blockDim.x + threadIdx.x;
    if (i >= n) return;
    int4 c = coors[i];                       // (b, z, y, x)
    int flat = c.x * (NYv * NXv) + c.z * NXv + c.w;
    atomicMax(&idx_map[flat], i);            // device-scope, cross-XCD safe
}

// ---------------------------------------------------------------------------
// Kernel 2: gather. One block per (b, y, 64-wide x segment).
// Phase 1: stage 64 pixels x 128 channels into LDS, coalesced 512B row reads.
// Phase 2: transposed float4 writes along x -> fully coalesced NCHW output.
// Writes every output element (implicit zero-fill for empty pixels).
// ---------------------------------------------------------------------------
__global__ __launch_bounds__(256) void gather_bev(
        const float* __restrict__ feat,
        const int* __restrict__ idx_map,
        float* __restrict__ out) {
    // +1 pad on leading dim: phase-2 read bank = (i + c) % 32 -> 2-way (free)
    __shared__ float tile[64 * 129];
    __shared__ int sv[64];

    const int bid  = blockIdx.x;
    const int xseg = bid & 7;            // NXv / 64 = 8
    const int y    = (bid >> 3) & (NYv - 1);
    const int b    = bid >> (3 + 9);
    const int tid  = threadIdx.x;

    const int pix_base = b * (NYv * NXv) + y * NXv + xseg * 64;
    if (tid < 64) sv[tid] = idx_map[pix_base + tid];
    __syncthreads();

    // Phase 1: wave w loads pixels p = w*16 .. w*16+15 (wave-uniform branch)
    const int wave = tid >> 6;
    const int lane = tid & 63;
    for (int k = 0; k < 16; ++k) {
        int p = wave * 16 + k;
        int v = sv[p];
        float2 f = make_float2(0.0f, 0.0f);
        if (v >= 0) {
            f = ((const float2*)(feat + (long)v * FEAT_C))[lane]; // 512B/wave
        }
        tile[p * 129 + 2 * lane]     = f.x;
        tile[p * 129 + 2 * lane + 1] = f.y;
    }
    __syncthreads();

    // Phase 2: 2048 float4 stores (128 c x 16 groups of 4 x), 8 iters/thread.
    // Within a wave: 16 lanes per channel -> 256B contiguous per channel row.
    const long plane = (long)NYv * NXv;
    float* out_base = out + (long)b * FEAT_C * plane + (long)y * NXv + xseg * 64;
    for (int it = 0; it < 8; ++it) {
        int j  = it * 256 + tid;
        int c  = j >> 4;                 // channel
        int i0 = (j & 15) << 2;          // x offset within segment
        float4 r;
        r.x = tile[(i0 + 0) * 129 + c];
        r.y = tile[(i0 + 1) * 129 + c];
        r.z = tile[(i0 + 2) * 129 + c];
        r.w = tile[(i0 + 3) * 129 + c];
        *(float4*)(out_base + (long)c * plane + i0) = r;  // 16B aligned
    }
}

extern "C" void kernel_launch(void* const* d_in, const int* in_sizes, int n_in,
                              void* d_out, int out_size, void* d_ws, size_t ws_size,
                              hipStream_t stream) {
    const float* feat  = (const float*)d_in[0];
    const int*   coors = (const int*)d_in[1];
    const int n = in_sizes[1] / 4;               // N voxels

    int* idx_map = (int*)d_ws;                   // needs 4 MiB of ws
    const size_t map_bytes = (size_t)NB * NYv * NXv * sizeof(int);

    // ws is re-poisoned to 0xAA before every timed call -> re-init every call.
    // memset 0xFF == int32 -1 (graph-capturable as a memset node).
    hipMemsetAsync(idx_map, 0xFF, map_bytes, stream);

    scatter_ids<<<(n + 255) / 256, 256, 0, stream>>>(
        (const int4*)coors, idx_map, n);

    const int nblocks = NB * NYv * (NXv / 64);   // 16384
    gather_bev<<<nblocks, 256, 0, stream>>>(feat, idx_map, (float*)d_out);
}

// Round 3
// 706.377 us; speedup vs baseline: 1.0310x; 1.0310x over previous
//
#include <hip/hip_runtime.h>

// Problem constants (fixed in reference setup_inputs)
#define FEAT_C 128
#define NB     4
#define NYv    512
#define NXv    512

typedef float vfloat4 __attribute__((ext_vector_type(4)));

// ---------------------------------------------------------------------------
// Kernel 1: scatter voxel ids into idx_map, last-write-wins (max id wins,
// matching numpy fancy-assignment duplicate semantics).
// idx_map pre-initialized to -1 (0xFF memset).
// ---------------------------------------------------------------------------
__global__ void scatter_ids(const int4* __restrict__ coors,
                            int* __restrict__ idx_map, int n) {
    int i = blockIdx.x * blockDim.x + threadIdx.x;
    if (i >= n) return;
    int4 c = coors[i];                       // (b, z, y, x)
    int flat = c.x * (NYv * NXv) + c.z * NXv + c.w;
    atomicMax(&idx_map[flat], i);            // device-scope, cross-XCD safe
}

// ---------------------------------------------------------------------------
// Kernel 2: gather. One block per (b, y, 64-wide x segment).
// Phase 1: stage 64 pixels x 128 channels into LDS via float4 loads
//          (2 pixels per wave-issue, 1 KiB/instruction), ds_write_b128.
// Phase 2: transposed float4 writes along x -> fully coalesced NCHW output.
// LDS layout XOR-swizzled: element (p,c) at word p*128 + (c ^ 4*((p>>2)&7)).
//   Phase-1 b128 writes: aligned (both terms multiple of 4), all banks 4x
//   (inherent minimum for 1 KiB/wave). Phase-2 b32 reads: bank =
//   (c ^ 4*(m&7)) % 32 -> exactly 2 lanes/bank = free (m136).
// Writes every output element (implicit zero-fill for empty pixels).
// ---------------------------------------------------------------------------
__global__ __launch_bounds__(256) void gather_bev(
        const float* __restrict__ feat,
        const int* __restrict__ idx_map,
        float* __restrict__ out) {
    __shared__ float tile[64 * FEAT_C];      // 32 KiB, swizzled
    __shared__ int sv[64];

    const int bid  = blockIdx.x;
    const int xseg = bid & 7;            // NXv / 64 = 8
    const int y    = (bid >> 3) & (NYv - 1);
    const int b    = bid >> (3 + 9);
    const int tid  = threadIdx.x;

    const int pix_base = b * (NYv * NXv) + y * NXv + xseg * 64;
    if (tid < 64) sv[tid] = idx_map[pix_base + tid];
    __syncthreads();

    // Phase 1: wave w owns pixels w*16 .. w*16+15. Each iteration loads TWO
    // pixel rows: lanes 0-31 -> pixel p, lanes 32-63 -> pixel p+1.
    const int wave = tid >> 6;
    const int lane = tid & 63;
    const int half = lane >> 5;          // 0 or 1
    const int l    = lane & 31;          // float4 slot within a row
#pragma unroll
    for (int k = 0; k < 8; ++k) {
        const int p = wave * 16 + 2 * k + half;
        const int v = sv[p];
        vfloat4 f = {0.f, 0.f, 0.f, 0.f};
        if (v >= 0) {
            f = ((const vfloat4*)(feat + v * FEAT_C))[l];   // 1 KiB / wave
        }
        const int sw   = 4 * ((p >> 2) & 7);
        const int word = p * FEAT_C + ((4 * l) ^ sw);
        *(vfloat4*)&tile[word] = f;       // ds_write_b128, aligned
    }
    __syncthreads();

    // Phase 2: 2048 float4 stores (128 c x 16 groups of 4 x), 8 iters/thread.
    // Within a wave: 16 lanes per channel -> 256B contiguous per channel row.
    const long plane = (long)NYv * NXv;
    float* out_base = out + (long)b * FEAT_C * plane + (long)y * NXv + xseg * 64;
#pragma unroll
    for (int it = 0; it < 8; ++it) {
        const int j  = it * 256 + tid;
        const int c  = j >> 4;                 // channel
        const int m  = j & 15;
        const int i0 = m << 2;                 // x offset within segment
        const int cs = c ^ (4 * (m & 7));      // swizzled channel slot
        vfloat4 r;
        r.x = tile[(i0 + 0) * FEAT_C + cs];
        r.y = tile[(i0 + 1) * FEAT_C + cs];
        r.z = tile[(i0 + 2) * FEAT_C + cs];
        r.w = tile[(i0 + 3) * FEAT_C + cs];
        __builtin_nontemporal_store(r, (vfloat4*)(out_base + (long)c * plane + i0));
    }
}

extern "C" void kernel_launch(void* const* d_in, const int* in_sizes, int n_in,
                              void* d_out, int out_size, void* d_ws, size_t ws_size,
                              hipStream_t stream) {
    const float* feat  = (const float*)d_in[0];
    const int*   coors = (const int*)d_in[1];
    const int n = in_sizes[1] / 4;               // N voxels

    int* idx_map = (int*)d_ws;                   // 4 MiB of ws
    const size_t map_bytes = (size_t)NB * NYv * NXv * sizeof(int);

    // ws is re-poisoned to 0xAA before every timed call -> re-init every call.
    // memset 0xFF == int32 -1 (graph-capturable as a memset node).
    (void)hipMemsetAsync(idx_map, 0xFF, map_bytes, stream);

    scatter_ids<<<(n + 255) / 256, 256, 0, stream>>>(
        (const int4*)coors, idx_map, n);

    const int nblocks = NB * NYv * (NXv / 64);   // 16384
    gather_bev<<<nblocks, 256, 0, stream>>>(feat, idx_map, (float*)d_out);
}